// Round 11
// baseline (56.352 us; speedup 1.0000x reference)
//
#include <hip/hip_runtime.h>
#include <math.h>

// LinearGating: B=4,S=4096,D=2048,E=64,K=2 -> N=16384 rows
// out (flat f32): [weights N*64][indices N*2 (as float)][logits N*64][probs N*64]
//
// fp16 split-3 MFMA GEMM: C[N x 128] = X[N x 2048] @ [Wg|Wn]
//   x = h + d, w = H + D;  acc1 += h*H ; acc2 += h*(D*2^6) + (d*2^6)*H
//   C = acc1 + acc2 * 2^-6
// R11: COALESCED x staging. global_load_lds with inverse-swizzled per-lane
// global source + linear LDS dest (rule #21): each wave DMAs 8 rows x 128B
// contiguous; XOR(row&7) chunk swizzle kills the 32-row column bank conflict
// on fragment reads. Convert f32->f16 split in compute (~60 VALU/iter,
// hidden by 4 waves/SIMD). B global->reg depth-2 via 3 static sets.
// One s_barrier + counted vmcnt(10) per iter (A-DMAs only; B compiler-tracked).

typedef _Float16 f16;
typedef f16  f16x8  __attribute__((ext_vector_type(8)));
typedef float f32x16 __attribute__((ext_vector_type(16)));

constexpr int NROWS = 16384;
constexpr int DDIM  = 2048;
constexpr int NE    = 64;
constexpr int BM    = 32;
constexpr int KI    = 32;                 // k per iteration per half
constexpr int NITER = 1024 / KI;          // 32
constexpr float NSCALE = 1.0f / 4096.0f;

// LDS: A raw-f32 swizzled tiles [0,32K): buf(4) x half(2) x [32 rows][128B]
//      merge mg [32K,48K): [32][128] f32 ; lgf reuses [0,16896) at end
__device__ __forceinline__ int a_base(int buf, int h) {
    return (buf * 2 + h) * 4096;
}

__device__ __forceinline__ float softplus_f(float x) {
    return fmaxf(x, 0.0f) + log1pf(expf(-fabsf(x)));
}

__device__ __forceinline__ void gload_lds16(const void* g, void* l) {
    __builtin_amdgcn_global_load_lds(
        (const __attribute__((address_space(1))) void*)g,
        (__attribute__((address_space(3))) void*)l, 16, 0, 0);
}

#define PIPE_BAR(N) do {                                                   \
    asm volatile("s_waitcnt vmcnt(" #N ") lgkmcnt(0)" ::: "memory");       \
    __builtin_amdgcn_sched_barrier(0);                                     \
    __builtin_amdgcn_s_barrier();                                          \
    __builtin_amdgcn_sched_barrier(0);                                     \
} while (0)

// ---------------- W prep: fragment-ordered fp16 {H, D*2^6} ----------------
// blob(S 0..127, f 0..3, v 0..1): lane l, elem j = Wcat[S*16+(l>>5)*8+j][f*32+(l&31)]
__global__ __launch_bounds__(256) void wprep_kernel(
    const float* __restrict__ Wg, const float* __restrict__ Wn,
    f16* __restrict__ ws)
{
    int t = blockIdx.x * 256 + threadIdx.x;    // 0..32767
    int S = t >> 8;
    int f = (t >> 6) & 3;
    int l = t & 63;
    int k0  = S * 16 + (l >> 5) * 8;
    int col = f * 32 + (l & 31);
    const float* src = (col < NE) ? (Wg + col) : (Wn + col - NE);
    f16x8 hp, lp;
    #pragma unroll
    for (int j = 0; j < 8; ++j) {
        float w  = src[(size_t)(k0 + j) * NE];
        f16 h    = (f16)w;
        float hf = (float)h;
        hp[j] = h;
        lp[j] = (f16)((w - hf) * 64.0f);
    }
    size_t base = (size_t)(S * 4 + f) * 1024;   // f16 units
    *(f16x8*)(ws + base + l * 8)       = hp;
    *(f16x8*)(ws + base + 512 + l * 8) = lp;
}

// ---------------- main fused kernel ----------------
__global__ __launch_bounds__(512, 4) void gemm_gating(
    const float* __restrict__ x, const f16* __restrict__ wfrag,
    const float* __restrict__ noise,
    float* __restrict__ out_w, float* __restrict__ out_idx,
    float* __restrict__ out_logits, float* __restrict__ out_probs)
{
    __shared__ __align__(16) char smem[49152];
    const int tid = threadIdx.x;
    const int l   = tid & 63;
    const int w   = tid >> 6;      // 0..7
    const int h   = w >> 2;        // compute: k-half
    const int f   = w & 3;         // compute: col quad (cols f*32..+31)
    const int row0 = blockIdx.x * BM;

    f32x16 acc1, acc2;
    #pragma unroll
    for (int r = 0; r < 16; ++r) { acc1[r] = 0.0f; acc2[r] = 0.0f; }

    // --- A staging: wave w DMAs rows rg*8..+7 of half hs, COALESCED ---
    // lane l: row sr = rg*8 + (l>>3); global chunk sc = (l&7) ^ (l>>3)
    // LDS dest linear (base + l*16)  =>  LDS[r][c] holds global chunk c^(r&7)
    const int hs = w >> 2, rg = w & 3;
    const int sr = rg * 8 + (l >> 3);
    const int sc = (l & 7) ^ (l >> 3);
    const float* aSrc = x + (size_t)(row0 + sr) * DDIM + hs * 1024 + sc * 4;
    char* aDst = smem;   // + a_base(buf,hs) + rg*1024 + l*16 (computed per call)
    auto dmaA = [&](int t) {
        gload_lds16(aSrc + (size_t)t * KI,
                    aDst + a_base((t) & 3, hs) + rg * 1024 + l * 16);
    };

    // --- B: wave-private, global->reg, depth-2 via 3 static sets ---
    const f16* bBase = wfrag + (size_t)f * 1024 + l * 8;
#define LOADB(t, H0, L0, H1, L1) do {                                       \
        const f16* _p = bBase + (size_t)(h * 64 + (t) * 2) * 4096;          \
        H0 = *(const f16x8*)_p;          L0 = *(const f16x8*)(_p + 512);    \
        H1 = *(const f16x8*)(_p + 4096); L1 = *(const f16x8*)(_p + 4608);   \
    } while (0)

    const int R   = l & 31;
    const int swz = R & 7;
    auto compute = [&](int t, const f16x8& Bh0, const f16x8& Bl0,
                              const f16x8& Bh1, const f16x8& Bl1) {
        const char* tile = smem + a_base(t & 3, h) + R * 128;
        #pragma unroll
        for (int s = 0; s < 2; ++s) {
            int g0 = s * 4 + (l >> 5) * 2;
            float4 a0 = *(const float4*)(tile + ((g0 ^ swz) * 16));
            float4 a1 = *(const float4*)(tile + (((g0 + 1) ^ swz) * 16));
            float xs[8] = {a0.x, a0.y, a0.z, a0.w, a1.x, a1.y, a1.z, a1.w};
            f16x8 Ah, Al;
            #pragma unroll
            for (int j = 0; j < 8; ++j) {
                f16 hh   = (f16)xs[j];
                float hf = (float)hh;
                Ah[j] = hh;
                Al[j] = (f16)((xs[j] - hf) * 64.0f);
            }
            const f16x8& Bh = s ? Bh1 : Bh0;
            const f16x8& Bl = s ? Bl1 : Bl0;
            acc1 = __builtin_amdgcn_mfma_f32_32x32x16_f16(Ah, Bh, acc1, 0, 0, 0);
            acc2 = __builtin_amdgcn_mfma_f32_32x32x16_f16(Ah, Bl, acc2, 0, 0, 0);
            acc2 = __builtin_amdgcn_mfma_f32_32x32x16_f16(Al, Bh, acc2, 0, 0, 0);
        }
    };

    f16x8 s0a, s0b, s0c, s0d;   // B set 0
    f16x8 s1a, s1b, s1c, s1d;   // B set 1
    f16x8 s2a, s2b, s2c, s2d;   // B set 2

    // -------- prologue: A(0..2) DMA; B(0),B(1) regs; 11 VMEM outstanding --------
    dmaA(0); dmaA(1); dmaA(2);
    LOADB(0, s0a, s0b, s0c, s0d);
    LOADB(1, s1a, s1b, s1c, s1d);

    // -------- steady: segs 0..29 (10 trips x 3), one bar+vmcnt(10) each --------
    for (int t = 0; t < 30; t += 3) {
        PIPE_BAR(10);
        if (t + 3 < NITER) dmaA(t + 3);
        LOADB(t + 2, s2a, s2b, s2c, s2d);
        compute(t, s0a, s0b, s0c, s0d);

        PIPE_BAR(10);
        if (t + 4 < NITER) dmaA(t + 4);
        LOADB(t + 3, s0a, s0b, s0c, s0d);
        compute(t + 1, s1a, s1b, s1c, s1d);

        PIPE_BAR(10);
        if (t + 5 < NITER) dmaA(t + 5);
        LOADB(t + 4, s1a, s1b, s1c, s1d);
        compute(t + 2, s2a, s2b, s2c, s2d);
    }
    // -------- tails: segs 30,31 --------
    PIPE_BAR(9);
    compute(30, s0a, s0b, s0c, s0d);
    PIPE_BAR(4);
    compute(31, s1a, s1b, s1c, s1d);
    __syncthreads();
#undef LOADB

    // ---- merge K-halves: h=1 waves write partial, h=0 adds ----
    float* mg  = (float*)(smem + 32768);   // [32][128]
    if (h == 1) {
        #pragma unroll
        for (int r = 0; r < 16; ++r) {
            float cv = fmaf(acc2[r], 0.015625f, acc1[r]);
            int row = (r & 3) + 8 * (r >> 2) + 4 * (l >> 5);
            int col = f * 32 + (l & 31);
            mg[row * 128 + col] = cv;
        }
    }
    __syncthreads();

    float* lgf = (float*)smem;             // [32][132]
    if (h == 0) {
        #pragma unroll
        for (int r = 0; r < 16; ++r) {
            float cv = fmaf(acc2[r], 0.015625f, acc1[r]);
            int row = (r & 3) + 8 * (r >> 2) + 4 * (l >> 5);
            int col = f * 32 + (l & 31);
            lgf[row * 132 + col] = cv + mg[row * 128 + col];
        }
    }
    __syncthreads();

    // ---- phase1: noise injection; 512 thr = 32 rows x 16 float4-chunks ----
    {
        const int pr = tid & 31;           // row
        const int c4 = tid >> 5;           // float4 chunk 0..15
        const int n1 = row0 + pr;
        float4 G  = *(const float4*)(lgf + pr * 132 + c4 * 4);
        float4 NL = *(const float4*)(lgf + pr * 132 + 64 + c4 * 4);
        float4 NZ = *(const float4*)(noise + (size_t)n1 * NE + c4 * 4);
        G.x += NZ.x * softplus_f(NL.x) * NSCALE;
        G.y += NZ.y * softplus_f(NL.y) * NSCALE;
        G.z += NZ.z * softplus_f(NL.z) * NSCALE;
        G.w += NZ.w * softplus_f(NL.w) * NSCALE;
        *(float4*)(lgf + pr * 132 + c4 * 4) = G;
        *(float4*)(out_logits + (size_t)n1 * NE + c4 * 4) = G;
    }
    __syncthreads();

    // ---- phase2: per-row top-2 + softmax; waves 0..3, 8 lanes/row ----
    if (w < 4) {
        const int g2   = l >> 3;           // row within wave's 8-row group
        const int c    = l & 7;            // expert chunk of 8
        const int row2 = w * 8 + g2;
        const int n2   = row0 + row2;

        float mv[8];
        {
            const float4* mr = (const float4*)(lgf + row2 * 132 + c * 8);
            float4 m0 = mr[0], m1 = mr[1];
            mv[0]=m0.x; mv[1]=m0.y; mv[2]=m0.z; mv[3]=m0.w;
            mv[4]=m1.x; mv[5]=m1.y; mv[6]=m1.z; mv[7]=m1.w;
        }
        float v0 = -INFINITY, v1 = -INFINITY;
        int i0 = 0, i1 = 0;
        #pragma unroll
        for (int j = 0; j < 8; ++j) {
            float v = mv[j]; int e = c * 8 + j;
            if (v > v0) { v1 = v0; i1 = i0; v0 = v; i0 = e; }
            else if (v > v1) { v1 = v; i1 = e; }
        }
        #pragma unroll
        for (int m = 1; m <= 4; m <<= 1) {
            float ov0 = __shfl_xor(v0, m), ov1 = __shfl_xor(v1, m);
            int   oi0 = __shfl_xor(i0, m), oi1 = __shfl_xor(i1, m);
            if (ov0 > v0) {
                bool keep = (v0 > ov1);
                v1 = keep ? v0 : ov1; i1 = keep ? i0 : oi1;
                v0 = ov0; i0 = oi0;
            } else if (ov0 > v1) {
                v1 = ov0; i1 = oi0;
            }
        }
        const int srcl = l & 56;
        v0 = __shfl(v0, srcl); i0 = __shfl(i0, srcl);
        v1 = __shfl(v1, srcl); i1 = __shfl(i1, srcl);

        float se = 0.0f;
        #pragma unroll
        for (int j = 0; j < 8; ++j) se += expf(mv[j] - v0);
        se += __shfl_xor(se, 1); se += __shfl_xor(se, 2); se += __shfl_xor(se, 4);
        float inv_se = 1.0f / se;

        float t  = expf(v1 - v0);
        float w0 = 1.0f / (1.0f + t);
        float w1 = t * w0;

        float pr[8], wt[8];
        #pragma unroll
        for (int j = 0; j < 8; ++j) {
            int e = c * 8 + j;
            pr[j] = expf(mv[j] - v0) * inv_se;
            wt[j] = (e == i0) ? w0 : ((e == i1) ? w1 : 0.0f);
        }
        *(float4*)(out_probs + (size_t)n2 * NE + c * 8)     = make_float4(pr[0], pr[1], pr[2], pr[3]);
        *(float4*)(out_probs + (size_t)n2 * NE + c * 8 + 4) = make_float4(pr[4], pr[5], pr[6], pr[7]);
        *(float4*)(out_w + (size_t)n2 * NE + c * 8)         = make_float4(wt[0], wt[1], wt[2], wt[3]);
        *(float4*)(out_w + (size_t)n2 * NE + c * 8 + 4)     = make_float4(wt[4], wt[5], wt[6], wt[7]);
        if (c == 0) {
            *(float2*)(out_idx + (size_t)n2 * 2) = make_float2((float)i0, (float)i1);
        }
    }
}

extern "C" void kernel_launch(void* const* d_in, const int* in_sizes, int n_in,
                              void* d_out, int out_size, void* d_ws, size_t ws_size,
                              hipStream_t stream) {
    (void)in_sizes; (void)n_in; (void)ws_size; (void)out_size;
    const float* x     = (const float*)d_in[0];
    const float* Wg    = (const float*)d_in[1];
    const float* Wn    = (const float*)d_in[2];
    const float* noise = (const float*)d_in[3];
    float* out        = (float*)d_out;
    float* out_w      = out;
    float* out_idx    = out + (size_t)NROWS * NE;
    float* out_logits = out_idx + (size_t)NROWS * 2;
    float* out_probs  = out_logits + (size_t)NROWS * NE;
    f16* wfrag = (f16*)d_ws;   // 1 MB

    wprep_kernel<<<128, 256, 0, stream>>>(Wg, Wn, wfrag);
    gemm_gating<<<NROWS / BM, 512, 0, stream>>>(
        x, wfrag, noise, out_w, out_idx, out_logits, out_probs);
}